// Round 8
// baseline (1347.253 us; speedup 1.0000x reference)
//
#include <hip/hip_runtime.h>
#include <hip/hip_bf16.h>
#include <stdint.h>

#define SEQ    2048
#define HIDDEN 4096
#define INTER  11008

typedef short bf16x8 __attribute__((ext_vector_type(8)));
typedef float f32x4  __attribute__((ext_vector_type(4)));
typedef unsigned short u16x8 __attribute__((ext_vector_type(8)));

__device__ __forceinline__ unsigned short f2bf(float f) {
    union { __hip_bfloat16 h; unsigned short u; } v;
    v.h = __float2bfloat16(f);
    return v.u;
}

__device__ __forceinline__ void gload_lds16(const void* g, void* lds) {
    __builtin_amdgcn_global_load_lds(
        (const __attribute__((address_space(1))) uint32_t*)g,
        (__attribute__((address_space(3))) uint32_t*)lds,
        16, 0, 0);
}

// ---------------------------------------------------------------------------
// x fp32 -> bf16
// ---------------------------------------------------------------------------
__global__ __launch_bounds__(256) void k_cvt_x(const float* __restrict__ x,
                                               unsigned short* __restrict__ xb) {
    int i = (blockIdx.x * 256 + threadIdx.x) * 4;
    float4 v = *(const float4*)(x + i);
    ushort4 o;
    o.x = f2bf(v.x); o.y = f2bf(v.y); o.z = f2bf(v.z); o.w = f2bf(v.w);
    *(ushort4*)(xb + i) = o;
}

// ---------------------------------------------------------------------------
// Weight dequant: int32 codes -> bf16. 8 codes/thread. group = i>>7.
// ---------------------------------------------------------------------------
__global__ __launch_bounds__(256) void k_dequant(
    const int* __restrict__ qw, const int* __restrict__ qz,
    const float* __restrict__ sc, unsigned short* __restrict__ w)
{
    size_t i = ((size_t)blockIdx.x * 256 + threadIdx.x) * 8;
    int gi = (int)(i >> 7);
    int   z = qz[gi];
    float s = sc[gi];
    float zs = -(float)z * s;
    int4 q0 = *(const int4*)(qw + i);
    int4 q1 = *(const int4*)(qw + i + 4);
    u16x8 o;
    o[0] = f2bf(fmaf((float)q0.x, s, zs));
    o[1] = f2bf(fmaf((float)q0.y, s, zs));
    o[2] = f2bf(fmaf((float)q0.z, s, zs));
    o[3] = f2bf(fmaf((float)q0.w, s, zs));
    o[4] = f2bf(fmaf((float)q1.x, s, zs));
    o[5] = f2bf(fmaf((float)q1.y, s, zs));
    o[6] = f2bf(fmaf((float)q1.z, s, zs));
    o[7] = f2bf(fmaf((float)q1.w, s, zs));
    *(u16x8*)(w + i) = o;
}

// ---------------------------------------------------------------------------
// Fused gate+up GEMM + SwiGLU -> h (bf16).
// 256 thr (4 waves: 2M x 2N). Tile 128(M) x 128(N), BK=64, single-buf 48 KB.
// Wave tile 64M x 64N for BOTH matrices: per K-tile 24 KB frag reads for
// 64 dual-MFMA (LDS cap ~55% vs R4's 45%). ~205 VGPR/thread, 8 waves/CU
// across 2 independent blocks -> barrier drains hidden by sibling block.
// Grid 1376 = 16 Mtiles x 86 Ntiles, XCD swizzle + M-siblings adjacent.
// ---------------------------------------------------------------------------
__global__ __launch_bounds__(256) void k_gate_up(
    const unsigned short* __restrict__ xb,   // [SEQ][HIDDEN] bf16
    const unsigned short* __restrict__ wg,   // [INTER][HIDDEN] bf16
    const unsigned short* __restrict__ wu,   // [INTER][HIDDEN] bf16
    const float* __restrict__ gbias, const float* __restrict__ ubias,
    unsigned short* __restrict__ h)          // [SEQ][INTER] bf16
{
    __shared__ __align__(16) unsigned short At[128 * 64]; // 16 KB, swizzled
    __shared__ __align__(16) unsigned short Bg[128 * 64]; // 16 KB
    __shared__ __align__(16) unsigned short Bu[128 * 64]; // 16 KB

    const int orig = blockIdx.x;                  // 1376 = 8 * 172
    const int swz  = (orig & 7) * 172 + (orig >> 3);
    const int mt   = swz & 15;                    // M-siblings adjacent
    const int nt   = swz >> 4;
    const int m0   = mt * 128;
    const int n0   = nt * 128;

    const int t    = threadIdx.x;
    const int lane = t & 63;
    const int wave = t >> 6;                      // 0..3
    const int wm   = (wave >> 1) * 64;            // 0,64
    const int wn   = (wave & 1) * 64;             // 0,64

    f32x4 accG[4][4], accU[4][4];
#pragma unroll
    for (int mi = 0; mi < 4; ++mi)
#pragma unroll
        for (int ni = 0; ni < 4; ++ni) {
            accG[mi][ni] = (f32x4){0.f, 0.f, 0.f, 0.f};
            accU[mi][ni] = (f32x4){0.f, 0.f, 0.f, 0.f};
        }

    for (int kt = 0; kt < HIDDEN / 64; ++kt) {
        const int k0 = kt * 64;

        // ---- stage A, Bg, Bu (each 128x64 = 1024 chunks, 4/thread) ----
#pragma unroll
        for (int cc = 0; cc < 4; ++cc) {
            int idx  = t + 256 * cc;
            int row  = idx >> 3;
            int scol = ((idx & 7) * 16) ^ ((row & 7) << 4);
            gload_lds16((const char*)(xb + (size_t)(m0 + row) * HIDDEN + k0) + scol,
                        (char*)At + idx * 16);
            gload_lds16((const char*)(wg + (size_t)(n0 + row) * HIDDEN + k0) + scol,
                        (char*)Bg + idx * 16);
            gload_lds16((const char*)(wu + (size_t)(n0 + row) * HIDDEN + k0) + scol,
                        (char*)Bu + idx * 16);
        }

        __syncthreads();

#pragma unroll
        for (int kk = 0; kk < 2; ++kk) {
            bf16x8 af[4], bg[4], bu[4];
            const int colb = kk * 64 + ((lane >> 4) * 16);
#pragma unroll
            for (int mi = 0; mi < 4; ++mi) {
                int row = wm + mi * 16 + (lane & 15);
                af[mi] = *(const bf16x8*)((const char*)At + row * 128 +
                                          (colb ^ ((row & 7) << 4)));
            }
#pragma unroll
            for (int ni = 0; ni < 4; ++ni) {
                int row = wn + ni * 16 + (lane & 15);
                int off = row * 128 + (colb ^ ((row & 7) << 4));
                bg[ni] = *(const bf16x8*)((const char*)Bg + off);
                bu[ni] = *(const bf16x8*)((const char*)Bu + off);
            }
            __builtin_amdgcn_s_setprio(1);
#pragma unroll
            for (int mi = 0; mi < 4; ++mi)
#pragma unroll
                for (int ni = 0; ni < 4; ++ni) {
                    accG[mi][ni] = __builtin_amdgcn_mfma_f32_16x16x32_bf16(
                        af[mi], bg[ni], accG[mi][ni], 0, 0, 0);
                    accU[mi][ni] = __builtin_amdgcn_mfma_f32_16x16x32_bf16(
                        af[mi], bu[ni], accU[mi][ni], 0, 0, 0);
                }
            __builtin_amdgcn_s_setprio(0);
        }

        __syncthreads();
    }

    // ---- epilogue: SwiGLU ----
#pragma unroll
    for (int ni = 0; ni < 4; ++ni) {
        int col = n0 + wn + ni * 16 + (lane & 15);
        float gb = gbias[col], ub = ubias[col];
#pragma unroll
        for (int mi = 0; mi < 4; ++mi) {
#pragma unroll
            for (int j = 0; j < 4; ++j) {
                int row = m0 + wm + mi * 16 + ((lane >> 4) * 4) + j;
                float g = accG[mi][ni][j] + gb;
                float u = accU[mi][ni][j] + ub;
                float sig = 1.f / (1.f + __expf(-g));
                h[(size_t)row * INTER + col] = f2bf(g * sig * u);
            }
        }
    }
}

// ---------------------------------------------------------------------------
// Down GEMM: y = h @ Wd^T + bias (fp32 out).
// 256 thr (4 waves: 2M x 2N). Tile 256(M) x 128(N), BK=64, single-buf 48 KB.
// Wave tile 128M x 64N (acc 128): 24 KB frag reads / 64 MFMA -> cap ~55%.
// Grid 256 = 8 Mtiles x 32 Ntiles, XCD swizzle + M-siblings adjacent.
// ---------------------------------------------------------------------------
__global__ __launch_bounds__(256) void k_down(
    const unsigned short* __restrict__ h,    // [SEQ][INTER] bf16
    const unsigned short* __restrict__ wd,   // [HIDDEN][INTER] bf16
    const float* __restrict__ dbias,
    float* __restrict__ y)                   // [SEQ][HIDDEN] fp32
{
    __shared__ __align__(16) unsigned short At[256 * 64]; // 32 KB, swizzled
    __shared__ __align__(16) unsigned short Bd[128 * 64]; // 16 KB

    const int orig = blockIdx.x;                  // 256 = 8 * 32
    const int swz  = (orig & 7) * 32 + (orig >> 3);
    const int mt   = swz & 7;                     // 8 M-tiles (BM=256)
    const int nt   = swz >> 3;                    // 32 N-tiles
    const int m0   = mt * 256;
    const int n0   = nt * 128;

    const int t    = threadIdx.x;
    const int lane = t & 63;
    const int wave = t >> 6;
    const int wm   = (wave >> 1) * 128;           // 0,128
    const int wn   = (wave & 1) * 64;             // 0,64

    f32x4 acc[8][4];
#pragma unroll
    for (int mi = 0; mi < 8; ++mi)
#pragma unroll
        for (int ni = 0; ni < 4; ++ni)
            acc[mi][ni] = (f32x4){0.f, 0.f, 0.f, 0.f};

    for (int kt = 0; kt < INTER / 64; ++kt) {
        const int k0 = kt * 64;

        // ---- stage A (256x64 = 2048 chunks, 8/thread) ----
#pragma unroll
        for (int cc = 0; cc < 8; ++cc) {
            int idx  = t + 256 * cc;
            int row  = idx >> 3;
            int scol = ((idx & 7) * 16) ^ ((row & 7) << 4);
            gload_lds16((const char*)(h + (size_t)(m0 + row) * INTER + k0) + scol,
                        (char*)At + idx * 16);
        }
        // ---- stage B (128x64 = 1024 chunks, 4/thread) ----
#pragma unroll
        for (int cc = 0; cc < 4; ++cc) {
            int idx  = t + 256 * cc;
            int row  = idx >> 3;
            int scol = ((idx & 7) * 16) ^ ((row & 7) << 4);
            gload_lds16((const char*)(wd + (size_t)(n0 + row) * INTER + k0) + scol,
                        (char*)Bd + idx * 16);
        }

        __syncthreads();

#pragma unroll
        for (int kk = 0; kk < 2; ++kk) {
            bf16x8 af[8], bd[4];
            const int colb = kk * 64 + ((lane >> 4) * 16);
#pragma unroll
            for (int mi = 0; mi < 8; ++mi) {
                int row = wm + mi * 16 + (lane & 15);
                af[mi] = *(const bf16x8*)((const char*)At + row * 128 +
                                          (colb ^ ((row & 7) << 4)));
            }
#pragma unroll
            for (int ni = 0; ni < 4; ++ni) {
                int row = wn + ni * 16 + (lane & 15);
                bd[ni] = *(const bf16x8*)((const char*)Bd + row * 128 +
                                          (colb ^ ((row & 7) << 4)));
            }
            __builtin_amdgcn_s_setprio(1);
#pragma unroll
            for (int mi = 0; mi < 8; ++mi)
#pragma unroll
                for (int ni = 0; ni < 4; ++ni)
                    acc[mi][ni] = __builtin_amdgcn_mfma_f32_16x16x32_bf16(
                        af[mi], bd[ni], acc[mi][ni], 0, 0, 0);
            __builtin_amdgcn_s_setprio(0);
        }

        __syncthreads();
    }

#pragma unroll
    for (int ni = 0; ni < 4; ++ni) {
        int col = n0 + wn + ni * 16 + (lane & 15);
        float db = dbias[col];
#pragma unroll
        for (int mi = 0; mi < 8; ++mi) {
#pragma unroll
            for (int j = 0; j < 4; ++j) {
                int row = m0 + wm + mi * 16 + ((lane >> 4) * 4) + j;
                y[(size_t)row * HIDDEN + col] = acc[mi][ni][j] + db;
            }
        }
    }
}

// ---------------------------------------------------------------------------
extern "C" void kernel_launch(void* const* d_in, const int* in_sizes, int n_in,
                              void* d_out, int out_size, void* d_ws, size_t ws_size,
                              hipStream_t stream) {
    const float* x    = (const float*)d_in[0];
    const int*   gqw  = (const int*)d_in[1];
    const int*   gqz  = (const int*)d_in[2];
    const float* gsc  = (const float*)d_in[3];
    const float* gbia = (const float*)d_in[4];
    const int*   uqw  = (const int*)d_in[5];
    const int*   uqz  = (const int*)d_in[6];
    const float* usc  = (const float*)d_in[7];
    const float* ubia = (const float*)d_in[8];
    const int*   dqw  = (const int*)d_in[9];
    const int*   dqz  = (const int*)d_in[10];
    const float* dsc  = (const float*)d_in[11];
    const float* dbia = (const float*)d_in[12];
    float* y = (float*)d_out;

    const size_t N_XB = (size_t)SEQ * HIDDEN;
    const size_t N_H  = (size_t)SEQ * INTER;
    const size_t N_W  = (size_t)INTER * HIDDEN;

    unsigned short* xb  = (unsigned short*)d_ws;
    unsigned short* hh  = xb + N_XB;
    unsigned short* wgb = hh + N_H;
    unsigned short* wub = wgb + N_W;
    unsigned short* wdb = wgb;                 // reused after k_gate_up

    const int dq_blocks = (int)(N_W / 2048);   // 22016

    k_cvt_x<<<(SEQ * HIDDEN) / 1024, 256, 0, stream>>>(x, xb);
    k_dequant<<<dq_blocks, 256, 0, stream>>>(gqw, gqz, gsc, wgb);
    k_dequant<<<dq_blocks, 256, 0, stream>>>(uqw, uqz, usc, wub);
    k_gate_up<<<dim3(1376), 256, 0, stream>>>(xb, wgb, wub, gbia, ubia, hh);
    k_dequant<<<dq_blocks, 256, 0, stream>>>(dqw, dqz, dsc, wdb);
    k_down<<<dim3(256), 256, 0, stream>>>(hh, wdb, dbia, y);
}

// Round 9
// 700.833 us; speedup vs baseline: 1.9224x; 1.9224x over previous
//
#include <hip/hip_runtime.h>
#include <hip/hip_bf16.h>
#include <stdint.h>

#define SEQ    2048
#define HIDDEN 4096
#define INTER  11008

typedef short bf16x8 __attribute__((ext_vector_type(8)));
typedef float f32x4  __attribute__((ext_vector_type(4)));
typedef unsigned short u16x8 __attribute__((ext_vector_type(8)));

__device__ __forceinline__ unsigned short f2bf(float f) {
    union { __hip_bfloat16 h; unsigned short u; } v;
    v.h = __float2bfloat16(f);
    return v.u;
}

__device__ __forceinline__ void gload_lds16(const void* g, void* lds) {
    __builtin_amdgcn_global_load_lds(
        (const __attribute__((address_space(1))) uint32_t*)g,
        (__attribute__((address_space(3))) uint32_t*)lds,
        16, 0, 0);
}

// ---------------------------------------------------------------------------
// Dequant work unit: one 512-thread block handles 4096 codes.
// ---------------------------------------------------------------------------
__device__ __forceinline__ void deq_block(
    const int* __restrict__ qw, const int* __restrict__ qz,
    const float* __restrict__ sc, unsigned short* __restrict__ w,
    int db, int t)
{
    size_t i = (size_t)db * 4096 + (size_t)t * 8;
    int gi = (int)(i >> 7);
    int   z = qz[gi];
    float s = sc[gi];
    float zs = -(float)z * s;
    int4 q0 = *(const int4*)(qw + i);
    int4 q1 = *(const int4*)(qw + i + 4);
    u16x8 o;
    o[0] = f2bf(fmaf((float)q0.x, s, zs));
    o[1] = f2bf(fmaf((float)q0.y, s, zs));
    o[2] = f2bf(fmaf((float)q0.z, s, zs));
    o[3] = f2bf(fmaf((float)q0.w, s, zs));
    o[4] = f2bf(fmaf((float)q1.x, s, zs));
    o[5] = f2bf(fmaf((float)q1.y, s, zs));
    o[6] = f2bf(fmaf((float)q1.z, s, zs));
    o[7] = f2bf(fmaf((float)q1.w, s, zs));
    *(u16x8*)(w + i) = o;
}

// ---------------------------------------------------------------------------
// Prep kernel: cvt x (blocks 0..2047) + dequant gate (2048..13055)
// + dequant up (13056..24063). All independent.
// ---------------------------------------------------------------------------
__global__ __launch_bounds__(512) void k_prep(
    const float* __restrict__ x, unsigned short* __restrict__ xb,
    const int* __restrict__ gqw, const int* __restrict__ gqz,
    const float* __restrict__ gsc, unsigned short* __restrict__ wgb,
    const int* __restrict__ uqw, const int* __restrict__ uqz,
    const float* __restrict__ usc, unsigned short* __restrict__ wub)
{
    const int bid = blockIdx.x;
    const int t   = threadIdx.x;
    if (bid < 2048) {
        size_t i = ((size_t)bid * 512 + t) * 8;
        float4 v0 = *(const float4*)(x + i);
        float4 v1 = *(const float4*)(x + i + 4);
        u16x8 o;
        o[0] = f2bf(v0.x); o[1] = f2bf(v0.y); o[2] = f2bf(v0.z); o[3] = f2bf(v0.w);
        o[4] = f2bf(v1.x); o[5] = f2bf(v1.y); o[6] = f2bf(v1.z); o[7] = f2bf(v1.w);
        *(u16x8*)(xb + i) = o;
    } else if (bid < 13056) {
        deq_block(gqw, gqz, gsc, wgb, bid - 2048, t);
    } else {
        deq_block(uqw, uqz, usc, wub, bid - 13056, t);
    }
}

// Standalone down-dequant (fallback path when ws is too small to de-alias).
__global__ __launch_bounds__(512) void k_deq_fb(
    const int* __restrict__ qw, const int* __restrict__ qz,
    const float* __restrict__ sc, unsigned short* __restrict__ w)
{
    deq_block(qw, qz, sc, w, blockIdx.x, threadIdx.x);
}

// ---------------------------------------------------------------------------
// Fused gate+up GEMM + SwiGLU -> h (bf16)  [R4-proven core + XCD swizzle]
// 512 thr (8 waves: 2M x 4N). Tile 128x128, BK=64, single-buf 48 KB,
// 2 blocks/CU (regs 60+64acc = 124 <= 128). Grid 1376 GEMM blocks
// (+ optional 11008 down-dequant blocks co-scheduled, blockIdx >= 1376).
// ---------------------------------------------------------------------------
__global__ __launch_bounds__(512) void k_gate_up(
    const unsigned short* __restrict__ xb,   // [SEQ][HIDDEN] bf16
    const unsigned short* __restrict__ wg,   // [INTER][HIDDEN] bf16
    const unsigned short* __restrict__ wu,   // [INTER][HIDDEN] bf16
    const float* __restrict__ gbias, const float* __restrict__ ubias,
    unsigned short* __restrict__ h,          // [SEQ][INTER] bf16
    const int* __restrict__ dqw, const int* __restrict__ dqz,
    const float* __restrict__ dsc, unsigned short* __restrict__ wdb)
{
    __shared__ __align__(16) unsigned short At[128 * 64]; // 16 KB, swizzled
    __shared__ __align__(16) unsigned short Bg[128 * 64]; // 16 KB
    __shared__ __align__(16) unsigned short Bu[128 * 64]; // 16 KB

    if (blockIdx.x >= 1376) {        // co-scheduled down-dequant block
        deq_block(dqw, dqz, dsc, wdb, blockIdx.x - 1376, threadIdx.x);
        return;
    }

    const int orig = blockIdx.x;                  // 1376 = 8 * 172
    const int swz  = (orig & 7) * 172 + (orig >> 3);
    const int mt   = swz & 15;
    const int nt   = swz >> 4;
    const int m0   = mt * 128;
    const int n0   = nt * 128;

    const int t    = threadIdx.x;
    const int lane = t & 63;
    const int wave = t >> 6;
    const int wm = (wave >> 2) * 64;
    const int wn = (wave & 3) * 32;

    f32x4 accG[4][2], accU[4][2];
#pragma unroll
    for (int mi = 0; mi < 4; ++mi)
#pragma unroll
        for (int ni = 0; ni < 2; ++ni) {
            accG[mi][ni] = (f32x4){0.f, 0.f, 0.f, 0.f};
            accU[mi][ni] = (f32x4){0.f, 0.f, 0.f, 0.f};
        }

    for (int kt = 0; kt < HIDDEN / 64; ++kt) {
        const int k0 = kt * 64;

#pragma unroll
        for (int cc = 0; cc < 2; ++cc) {
            int idx  = t + 512 * cc;
            int row  = idx >> 3;
            int scol = ((idx & 7) * 16) ^ ((row & 7) << 4);
            gload_lds16((const char*)(xb + (size_t)(m0 + row) * HIDDEN + k0) + scol,
                        (char*)At + idx * 16);
            gload_lds16((const char*)(wg + (size_t)(n0 + row) * HIDDEN + k0) + scol,
                        (char*)Bg + idx * 16);
            gload_lds16((const char*)(wu + (size_t)(n0 + row) * HIDDEN + k0) + scol,
                        (char*)Bu + idx * 16);
        }

        __syncthreads();

#pragma unroll
        for (int kk = 0; kk < 2; ++kk) {
            bf16x8 af[4], bg[2], bu[2];
#pragma unroll
            for (int mi = 0; mi < 4; ++mi) {
                int row  = wm + mi * 16 + (lane & 15);
                int colb = kk * 64 + ((lane >> 4) * 16);
                af[mi] = *(const bf16x8*)((const char*)At + row * 128 +
                                          (colb ^ ((row & 7) << 4)));
            }
#pragma unroll
            for (int ni = 0; ni < 2; ++ni) {
                int row  = wn + ni * 16 + (lane & 15);
                int colb = kk * 64 + ((lane >> 4) * 16);
                int off  = row * 128 + (colb ^ ((row & 7) << 4));
                bg[ni] = *(const bf16x8*)((const char*)Bg + off);
                bu[ni] = *(const bf16x8*)((const char*)Bu + off);
            }
            __builtin_amdgcn_s_setprio(1);
#pragma unroll
            for (int mi = 0; mi < 4; ++mi)
#pragma unroll
                for (int ni = 0; ni < 2; ++ni) {
                    accG[mi][ni] = __builtin_amdgcn_mfma_f32_16x16x32_bf16(
                        af[mi], bg[ni], accG[mi][ni], 0, 0, 0);
                    accU[mi][ni] = __builtin_amdgcn_mfma_f32_16x16x32_bf16(
                        af[mi], bu[ni], accU[mi][ni], 0, 0, 0);
                }
            __builtin_amdgcn_s_setprio(0);
        }

        __syncthreads();
    }

#pragma unroll
    for (int ni = 0; ni < 2; ++ni) {
        int col = n0 + wn + ni * 16 + (lane & 15);
        float gb = gbias[col], ub = ubias[col];
#pragma unroll
        for (int mi = 0; mi < 4; ++mi) {
#pragma unroll
            for (int j = 0; j < 4; ++j) {
                int row = m0 + wm + mi * 16 + ((lane >> 4) * 4) + j;
                float g = accG[mi][ni][j] + gb;
                float u = accU[mi][ni][j] + ub;
                float sig = 1.f / (1.f + __expf(-g));
                h[(size_t)row * INTER + col] = f2bf(g * sig * u);
            }
        }
    }
}

// ---------------------------------------------------------------------------
// Down GEMM: y = h @ Wd^T + bias (fp32 out). [R4-proven core + XCD swizzle]
// 512 thr, tile 128x128, BK=64. Grid 512 = 8 * 64.
// ---------------------------------------------------------------------------
__global__ __launch_bounds__(512) void k_down(
    const unsigned short* __restrict__ h,    // [SEQ][INTER] bf16
    const unsigned short* __restrict__ wd,   // [HIDDEN][INTER] bf16
    const float* __restrict__ dbias,
    float* __restrict__ y)                   // [SEQ][HIDDEN] fp32
{
    __shared__ __align__(16) unsigned short At[128 * 64]; // 16 KB
    __shared__ __align__(16) unsigned short Bd[128 * 64]; // 16 KB

    const int orig = blockIdx.x;                  // 512 = 8 * 64
    const int swz  = (orig & 7) * 64 + (orig >> 3);
    const int mt   = swz & 15;
    const int nt   = swz >> 4;
    const int m0   = mt * 128;
    const int n0   = nt * 128;

    const int t    = threadIdx.x;
    const int lane = t & 63;
    const int wave = t >> 6;
    const int wm = (wave >> 2) * 64;
    const int wn = (wave & 3) * 32;

    f32x4 acc[4][2];
#pragma unroll
    for (int mi = 0; mi < 4; ++mi)
#pragma unroll
        for (int ni = 0; ni < 2; ++ni)
            acc[mi][ni] = (f32x4){0.f, 0.f, 0.f, 0.f};

    for (int kt = 0; kt < INTER / 64; ++kt) {
        const int k0 = kt * 64;

#pragma unroll
        for (int cc = 0; cc < 2; ++cc) {
            int idx  = t + 512 * cc;
            int row  = idx >> 3;
            int scol = ((idx & 7) * 16) ^ ((row & 7) << 4);
            gload_lds16((const char*)(h + (size_t)(m0 + row) * INTER + k0) + scol,
                        (char*)At + idx * 16);
            gload_lds16((const char*)(wd + (size_t)(n0 + row) * INTER + k0) + scol,
                        (char*)Bd + idx * 16);
        }

        __syncthreads();

#pragma unroll
        for (int kk = 0; kk < 2; ++kk) {
            bf16x8 af[4], bd[2];
#pragma unroll
            for (int mi = 0; mi < 4; ++mi) {
                int row  = wm + mi * 16 + (lane & 15);
                int colb = kk * 64 + ((lane >> 4) * 16);
                af[mi] = *(const bf16x8*)((const char*)At + row * 128 +
                                          (colb ^ ((row & 7) << 4)));
            }
#pragma unroll
            for (int ni = 0; ni < 2; ++ni) {
                int row  = wn + ni * 16 + (lane & 15);
                int colb = kk * 64 + ((lane >> 4) * 16);
                bd[ni] = *(const bf16x8*)((const char*)Bd + row * 128 +
                                          (colb ^ ((row & 7) << 4)));
            }
            __builtin_amdgcn_s_setprio(1);
#pragma unroll
            for (int mi = 0; mi < 4; ++mi)
#pragma unroll
                for (int ni = 0; ni < 2; ++ni)
                    acc[mi][ni] = __builtin_amdgcn_mfma_f32_16x16x32_bf16(
                        af[mi], bd[ni], acc[mi][ni], 0, 0, 0);
            __builtin_amdgcn_s_setprio(0);
        }

        __syncthreads();
    }

#pragma unroll
    for (int ni = 0; ni < 2; ++ni) {
        int col = n0 + wn + ni * 16 + (lane & 15);
        float db = dbias[col];
#pragma unroll
        for (int mi = 0; mi < 4; ++mi) {
#pragma unroll
            for (int j = 0; j < 4; ++j) {
                int row = m0 + wm + mi * 16 + ((lane >> 4) * 4) + j;
                y[(size_t)row * HIDDEN + col] = acc[mi][ni][j] + db;
            }
        }
    }
}

// ---------------------------------------------------------------------------
extern "C" void kernel_launch(void* const* d_in, const int* in_sizes, int n_in,
                              void* d_out, int out_size, void* d_ws, size_t ws_size,
                              hipStream_t stream) {
    const float* x    = (const float*)d_in[0];
    const int*   gqw  = (const int*)d_in[1];
    const int*   gqz  = (const int*)d_in[2];
    const float* gsc  = (const float*)d_in[3];
    const float* gbia = (const float*)d_in[4];
    const int*   uqw  = (const int*)d_in[5];
    const int*   uqz  = (const int*)d_in[6];
    const float* usc  = (const float*)d_in[7];
    const float* ubia = (const float*)d_in[8];
    const int*   dqw  = (const int*)d_in[9];
    const int*   dqz  = (const int*)d_in[10];
    const float* dsc  = (const float*)d_in[11];
    const float* dbia = (const float*)d_in[12];
    float* y = (float*)d_out;

    const size_t N_XB = (size_t)SEQ * HIDDEN;      // 8.4M
    const size_t N_H  = (size_t)SEQ * INTER;       // 22.5M
    const size_t N_W  = (size_t)INTER * HIDDEN;    // 45.1M

    unsigned short* xb  = (unsigned short*)d_ws;
    unsigned short* hh  = xb + N_XB;
    unsigned short* wgb = hh + N_H;
    unsigned short* wub = wgb + N_W;

    const size_t need_big = (N_XB + N_H + 3 * N_W) * sizeof(unsigned short);
    const bool   big      = ws_size >= need_big;

    // prep: cvt + dequant gate + dequant up (2048 + 11008 + 11008 blocks)
    k_prep<<<dim3(24064), 512, 0, stream>>>(x, xb, gqw, gqz, gsc, wgb,
                                            uqw, uqz, usc, wub);

    if (big) {
        unsigned short* wdb = wub + N_W;           // de-aliased down weights
        // GEMM (1376) + co-scheduled down-dequant (11008) in one grid
        k_gate_up<<<dim3(1376 + 11008), 512, 0, stream>>>(
            xb, wgb, wub, gbia, ubia, hh, dqw, dqz, dsc, wdb);
        k_down<<<dim3(512), 512, 0, stream>>>(hh, wdb, dbia, y);
    } else {
        unsigned short* wdb = wgb;                 // alias: serial fallback
        k_gate_up<<<dim3(1376), 512, 0, stream>>>(
            xb, wgb, wub, gbia, ubia, hh, dqw, dqz, dsc, wdb);
        k_deq_fb<<<dim3(11008), 512, 0, stream>>>(dqw, dqz, dsc, wdb);
        k_down<<<dim3(512), 512, 0, stream>>>(hh, wdb, dbia, y);
    }
}

// Round 10
// 686.938 us; speedup vs baseline: 1.9612x; 1.0202x over previous
//
#include <hip/hip_runtime.h>
#include <hip/hip_bf16.h>
#include <stdint.h>

#define SEQ    2048
#define HIDDEN 4096
#define INTER  11008

typedef short bf16x8 __attribute__((ext_vector_type(8)));
typedef float f32x4  __attribute__((ext_vector_type(4)));
typedef float f32x16 __attribute__((ext_vector_type(16)));
typedef int   i32x4  __attribute__((ext_vector_type(4)));
typedef int   i32x16 __attribute__((ext_vector_type(16)));
typedef unsigned short u16x8 __attribute__((ext_vector_type(8)));

__device__ __forceinline__ unsigned short f2bf(float f) {
    union { __hip_bfloat16 h; unsigned short u; } v;
    v.h = __float2bfloat16(f);
    return v.u;
}

__device__ __forceinline__ void gload_lds16(const void* g, void* lds) {
    __builtin_amdgcn_global_load_lds(
        (const __attribute__((address_space(1))) uint32_t*)g,
        (__attribute__((address_space(3))) uint32_t*)lds,
        16, 0, 0);
}

// ---------------------------------------------------------------------------
// Prep: x -> int8 rows (per-row scale ax) ; gate/up codes -> int8 (q - z).
// Grid 24064 x 512: [0,2048) x-quant, [2048,13056) gate, [13056,24064) up.
// ---------------------------------------------------------------------------
__global__ __launch_bounds__(512) void k_prep(
    const float* __restrict__ x, signed char* __restrict__ xq,
    float* __restrict__ ax,
    const int* __restrict__ gqw, const int* __restrict__ gqz,
    signed char* __restrict__ wg8,
    const int* __restrict__ uqw, const int* __restrict__ uqz,
    signed char* __restrict__ wu8)
{
    const int bid = blockIdx.x;
    const int t   = threadIdx.x;
    if (bid < 2048) {
        __shared__ float wmx[8];
        const float* xr = x + (size_t)bid * HIDDEN + t * 8;
        float v[8]; float m = 0.f;
#pragma unroll
        for (int j = 0; j < 8; ++j) { v[j] = xr[j]; m = fmaxf(m, fabsf(v[j])); }
#pragma unroll
        for (int off = 32; off; off >>= 1) m = fmaxf(m, __shfl_xor(m, off));
        if ((t & 63) == 0) wmx[t >> 6] = m;
        __syncthreads();
        m = wmx[0];
#pragma unroll
        for (int w = 1; w < 8; ++w) m = fmaxf(m, wmx[w]);
        float inv = m > 0.f ? 127.f / m : 0.f;
        int q[8];
#pragma unroll
        for (int j = 0; j < 8; ++j) {
            int qi = (int)rintf(v[j] * inv);
            q[j] = qi < -127 ? -127 : (qi > 127 ? 127 : qi);
        }
        int w0 = (q[0]&255) | ((q[1]&255)<<8) | ((q[2]&255)<<16) | ((q[3]&255)<<24);
        int w1 = (q[4]&255) | ((q[5]&255)<<8) | ((q[6]&255)<<16) | ((q[7]&255)<<24);
        ((int2*)(xq + (size_t)bid * HIDDEN))[t] = make_int2(w0, w1);
        if (t == 0) ax[bid] = m / 127.f;
    } else {
        const int* qw; const int* qz; signed char* w8; int row;
        if (bid < 13056) { qw = gqw; qz = gqz; w8 = wg8; row = bid - 2048; }
        else             { qw = uqw; qz = uqz; w8 = wu8; row = bid - 13056; }
        size_t base = (size_t)row * HIDDEN + t * 8;
        int4 q0 = *(const int4*)(qw + base);
        int4 q1 = *(const int4*)(qw + base + 4);
        int z = qz[row * (HIDDEN / 128) + (t >> 4)];   // (t*8)>>7
        int w0 = ((q0.x-z)&255) | (((q0.y-z)&255)<<8) |
                 (((q0.z-z)&255)<<16) | (((q0.w-z)&255)<<24);
        int w1 = ((q1.x-z)&255) | (((q1.y-z)&255)<<8) |
                 (((q1.z-z)&255)<<16) | (((q1.w-z)&255)<<24);
        ((int2*)(w8 + (size_t)row * HIDDEN))[t] = make_int2(w0, w1);
    }
}

// ---------------------------------------------------------------------------
// Down-weight dequant work unit (bf16 out), 256 thr x 2048 codes.
// ---------------------------------------------------------------------------
__device__ __forceinline__ void deq_block256(
    const int* __restrict__ qw, const int* __restrict__ qz,
    const float* __restrict__ sc, unsigned short* __restrict__ w,
    int db, int t)
{
    size_t i = (size_t)db * 2048 + (size_t)t * 8;
    int gi = (int)(i >> 7);
    int   z = qz[gi];
    float s = sc[gi];
    float zs = -(float)z * s;
    int4 q0 = *(const int4*)(qw + i);
    int4 q1 = *(const int4*)(qw + i + 4);
    u16x8 o;
    o[0] = f2bf(fmaf((float)q0.x, s, zs));
    o[1] = f2bf(fmaf((float)q0.y, s, zs));
    o[2] = f2bf(fmaf((float)q0.z, s, zs));
    o[3] = f2bf(fmaf((float)q0.w, s, zs));
    o[4] = f2bf(fmaf((float)q1.x, s, zs));
    o[5] = f2bf(fmaf((float)q1.y, s, zs));
    o[6] = f2bf(fmaf((float)q1.z, s, zs));
    o[7] = f2bf(fmaf((float)q1.w, s, zs));
    *(u16x8*)(w + i) = o;
}

// ---------------------------------------------------------------------------
// W8A8 fused gate+up GEMM + SwiGLU -> h (bf16).
// 256 thr (4 waves: 2M x 2N). Tile 128M x 64N, BK=128 (= one quant group).
// mfma_i32_32x32x32_i8; wave tile 64M x 32N dual. i32 acc per tile, then
// acc_f32 += cvt(i32) * s[col,grp]; epilogue applies ax[row] + bias + SwiGLU.
// LDS 32 KB; regs ~128 acc + arch under launch_bounds(256,2) -> 2 blocks/CU.
// Grid 2752 GEMM (8x344 XCD swizzle, M-siblings adjacent) + 22016 deq blocks.
// ---------------------------------------------------------------------------
__global__ __launch_bounds__(256, 2) void k_gate_up_i8(
    const signed char* __restrict__ xq, const float* __restrict__ ax,
    const signed char* __restrict__ wg8, const signed char* __restrict__ wu8,
    const float* __restrict__ gsc, const float* __restrict__ usc,
    const float* __restrict__ gbias, const float* __restrict__ ubias,
    unsigned short* __restrict__ h,
    const int* __restrict__ dqw, const int* __restrict__ dqz,
    const float* __restrict__ dsc, unsigned short* __restrict__ wdb)
{
    __shared__ __align__(16) signed char At[128 * 128]; // 16 KB
    __shared__ __align__(16) signed char Bg[64 * 128];  // 8 KB
    __shared__ __align__(16) signed char Bu[64 * 128];  // 8 KB

    if (blockIdx.x >= 2752) {      // co-scheduled down-dequant
        deq_block256(dqw, dqz, dsc, wdb, blockIdx.x - 2752, threadIdx.x);
        return;
    }

    const int orig = blockIdx.x;                  // 2752 = 8 * 344
    const int swz  = (orig & 7) * 344 + (orig >> 3);
    const int mt   = swz & 15;                    // M-siblings adjacent
    const int nt   = swz >> 4;                    // 0..171
    const int m0   = mt * 128;
    const int n0   = nt * 64;

    const int t     = threadIdx.x;
    const int lane  = t & 63;
    const int wave  = t >> 6;
    const int wm    = (wave >> 1) * 64;           // 0,64
    const int wn    = (wave & 1) * 32;            // 0,32
    const int lrow  = lane & 31;
    const int khalf = lane >> 5;                  // 0/1
    const int col   = n0 + wn + lrow;             // this lane's output column

    f32x16 gF[2], uF[2];
#pragma unroll
    for (int mi = 0; mi < 2; ++mi)
#pragma unroll
        for (int j = 0; j < 16; ++j) { gF[mi][j] = 0.f; uF[mi][j] = 0.f; }

    for (int kt = 0; kt < HIDDEN / 128; ++kt) {
        const int k0 = kt * 128;

        // ---- stage A (128 rows x 128 B = 1024 chunks, 4/thread) ----
#pragma unroll
        for (int cc = 0; cc < 4; ++cc) {
            int idx = t + 256 * cc;
            int row = idx >> 3, sl = idx & 7;
            gload_lds16(xq + (size_t)(m0 + row) * HIDDEN + k0 + ((sl ^ (row & 7)) * 16),
                        (char*)At + idx * 16);
        }
        // ---- stage Bg/Bu (64 rows x 128 B = 512 chunks, 2/thread each) ----
#pragma unroll
        for (int cc = 0; cc < 2; ++cc) {
            int idx = t + 256 * cc;
            int row = idx >> 3, sl = idx & 7;
            int go  = (sl ^ (row & 7)) * 16;
            gload_lds16(wg8 + (size_t)(n0 + row) * HIDDEN + k0 + go, (char*)Bg + idx * 16);
            gload_lds16(wu8 + (size_t)(n0 + row) * HIDDEN + k0 + go, (char*)Bu + idx * 16);
        }

        __syncthreads();

        float sg = gsc[(size_t)col * (HIDDEN / 128) + kt];
        float su = usc[(size_t)col * (HIDDEN / 128) + kt];

        i32x16 gI[2], uI[2];
#pragma unroll
        for (int ks = 0; ks < 4; ++ks) {
            int slot = 2 * ks + khalf;
            int r0 = wm + lrow;
            int r1 = wm + 32 + lrow;
            int rb = wn + lrow;
            i32x4 a0  = *(const i32x4*)(At + r0 * 128 + ((slot ^ (r0 & 7)) * 16));
            i32x4 a1  = *(const i32x4*)(At + r1 * 128 + ((slot ^ (r1 & 7)) * 16));
            i32x4 bgv = *(const i32x4*)(Bg + rb * 128 + ((slot ^ (rb & 7)) * 16));
            i32x4 buv = *(const i32x4*)(Bu + rb * 128 + ((slot ^ (rb & 7)) * 16));
            __builtin_amdgcn_s_setprio(1);
            if (ks == 0) {
                i32x16 z16;
#pragma unroll
                for (int j = 0; j < 16; ++j) z16[j] = 0;
                gI[0] = __builtin_amdgcn_mfma_i32_32x32x32_i8(a0, bgv, z16, 0, 0, 0);
                gI[1] = __builtin_amdgcn_mfma_i32_32x32x32_i8(a1, bgv, z16, 0, 0, 0);
                uI[0] = __builtin_amdgcn_mfma_i32_32x32x32_i8(a0, buv, z16, 0, 0, 0);
                uI[1] = __builtin_amdgcn_mfma_i32_32x32x32_i8(a1, buv, z16, 0, 0, 0);
            } else {
                gI[0] = __builtin_amdgcn_mfma_i32_32x32x32_i8(a0, bgv, gI[0], 0, 0, 0);
                gI[1] = __builtin_amdgcn_mfma_i32_32x32x32_i8(a1, bgv, gI[1], 0, 0, 0);
                uI[0] = __builtin_amdgcn_mfma_i32_32x32x32_i8(a0, buv, uI[0], 0, 0, 0);
                uI[1] = __builtin_amdgcn_mfma_i32_32x32x32_i8(a1, buv, uI[1], 0, 0, 0);
            }
            __builtin_amdgcn_s_setprio(0);
        }

        __syncthreads();

        // ---- per-group rescale into fp32 accumulators ----
#pragma unroll
        for (int mi = 0; mi < 2; ++mi)
#pragma unroll
            for (int j = 0; j < 16; ++j) {
                gF[mi][j] = fmaf((float)gI[mi][j], sg, gF[mi][j]);
                uF[mi][j] = fmaf((float)uI[mi][j], su, uF[mi][j]);
            }
    }

    // ---- epilogue: apply ax[row], bias, SwiGLU; C/D 32x32 layout ----
    float gb = gbias[col], ub = ubias[col];
#pragma unroll
    for (int mi = 0; mi < 2; ++mi) {
#pragma unroll
        for (int j = 0; j < 16; ++j) {
            int row = m0 + wm + mi * 32 + (j & 3) + 8 * (j >> 2) + 4 * khalf;
            float axv = ax[row];
            float g = gF[mi][j] * axv + gb;
            float u = uF[mi][j] * axv + ub;
            float sig = 1.f / (1.f + __expf(-g));
            h[(size_t)row * INTER + col] = f2bf(g * sig * u);
        }
    }
}

// ---------------------------------------------------------------------------
// Down GEMM: y = h @ Wd^T + bias (fp32 out). [R9-proven, unchanged]
// 512 thr, tile 128x128, BK=64. Grid 512 = 8 * 64 XCD swizzle.
// ---------------------------------------------------------------------------
__global__ __launch_bounds__(512) void k_down(
    const unsigned short* __restrict__ h,
    const unsigned short* __restrict__ wd,
    const float* __restrict__ dbias,
    float* __restrict__ y)
{
    __shared__ __align__(16) unsigned short At[128 * 64];
    __shared__ __align__(16) unsigned short Bd[128 * 64];

    const int orig = blockIdx.x;
    const int swz  = (orig & 7) * 64 + (orig >> 3);
    const int mt   = swz & 15;
    const int nt   = swz >> 4;
    const int m0   = mt * 128;
    const int n0   = nt * 128;

    const int t    = threadIdx.x;
    const int lane = t & 63;
    const int wave = t >> 6;
    const int wm = (wave >> 2) * 64;
    const int wn = (wave & 3) * 32;

    f32x4 acc[4][2];
#pragma unroll
    for (int mi = 0; mi < 4; ++mi)
#pragma unroll
        for (int ni = 0; ni < 2; ++ni)
            acc[mi][ni] = (f32x4){0.f, 0.f, 0.f, 0.f};

    for (int kt = 0; kt < INTER / 64; ++kt) {
        const int k0 = kt * 64;

#pragma unroll
        for (int cc = 0; cc < 2; ++cc) {
            int idx  = t + 512 * cc;
            int row  = idx >> 3;
            int scol = ((idx & 7) * 16) ^ ((row & 7) << 4);
            gload_lds16((const char*)(h + (size_t)(m0 + row) * INTER + k0) + scol,
                        (char*)At + idx * 16);
            gload_lds16((const char*)(wd + (size_t)(n0 + row) * INTER + k0) + scol,
                        (char*)Bd + idx * 16);
        }

        __syncthreads();

#pragma unroll
        for (int kk = 0; kk < 2; ++kk) {
            bf16x8 af[4], bd[2];
#pragma unroll
            for (int mi = 0; mi < 4; ++mi) {
                int row  = wm + mi * 16 + (lane & 15);
                int colb = kk * 64 + ((lane >> 4) * 16);
                af[mi] = *(const bf16x8*)((const char*)At + row * 128 +
                                          (colb ^ ((row & 7) << 4)));
            }
#pragma unroll
            for (int ni = 0; ni < 2; ++ni) {
                int row  = wn + ni * 16 + (lane & 15);
                int colb = kk * 64 + ((lane >> 4) * 16);
                bd[ni] = *(const bf16x8*)((const char*)Bd + row * 128 +
                                          (colb ^ ((row & 7) << 4)));
            }
            __builtin_amdgcn_s_setprio(1);
#pragma unroll
            for (int mi = 0; mi < 4; ++mi)
#pragma unroll
                for (int ni = 0; ni < 2; ++ni)
                    acc[mi][ni] = __builtin_amdgcn_mfma_f32_16x16x32_bf16(
                        af[mi], bd[ni], acc[mi][ni], 0, 0, 0);
            __builtin_amdgcn_s_setprio(0);
        }

        __syncthreads();
    }

#pragma unroll
    for (int ni = 0; ni < 2; ++ni) {
        int col = n0 + wn + ni * 16 + (lane & 15);
        float db = dbias[col];
#pragma unroll
        for (int mi = 0; mi < 4; ++mi) {
#pragma unroll
            for (int j = 0; j < 4; ++j) {
                int row = m0 + wm + mi * 16 + ((lane >> 4) * 4) + j;
                y[(size_t)row * HIDDEN + col] = acc[mi][ni][j] + db;
            }
        }
    }
}

// ---------------------------------------------------------------------------
extern "C" void kernel_launch(void* const* d_in, const int* in_sizes, int n_in,
                              void* d_out, int out_size, void* d_ws, size_t ws_size,
                              hipStream_t stream) {
    const float* x    = (const float*)d_in[0];
    const int*   gqw  = (const int*)d_in[1];
    const int*   gqz  = (const int*)d_in[2];
    const float* gsc  = (const float*)d_in[3];
    const float* gbia = (const float*)d_in[4];
    const int*   uqw  = (const int*)d_in[5];
    const int*   uqz  = (const int*)d_in[6];
    const float* usc  = (const float*)d_in[7];
    const float* ubia = (const float*)d_in[8];
    const int*   dqw  = (const int*)d_in[9];
    const int*   dqz  = (const int*)d_in[10];
    const float* dsc  = (const float*)d_in[11];
    const float* dbia = (const float*)d_in[12];
    float* y = (float*)d_out;

    // ws layout (~234 MB; ws >= 332 MB proven by R9 big-path evidence)
    char* p = (char*)d_ws;
    signed char* xq = (signed char*)p;        p += (size_t)SEQ * HIDDEN;
    float* ax       = (float*)p;              p += (size_t)SEQ * 4;
    signed char* wg8 = (signed char*)p;       p += (size_t)INTER * HIDDEN;
    signed char* wu8 = (signed char*)p;       p += (size_t)INTER * HIDDEN;
    unsigned short* hh  = (unsigned short*)p; p += (size_t)SEQ * INTER * 2;
    unsigned short* wdb = (unsigned short*)p;

    k_prep<<<dim3(24064), 512, 0, stream>>>(x, xq, ax, gqw, gqz, wg8,
                                            uqw, uqz, wu8);
    k_gate_up_i8<<<dim3(2752 + 22016), 256, 0, stream>>>(
        xq, ax, wg8, wu8, gsc, usc, gbia, ubia, hh, dqw, dqz, dsc, wdb);
    k_down<<<dim3(512), 512, 0, stream>>>(hh, wdb, dbia, y);
}